// Round 16
// baseline (267.324 us; speedup 1.0000x reference)
//
#include <hip/hip_runtime.h>
#include <hip/hip_bf16.h>

#define NGRAPH  64
#define TOPO_D  16
#define NBLK    512     // binning blocks (pass A); E=1.6M -> 3125 edges/block
#define MAXB    512     // LDS cap for bucket arrays (nb2 = ceil(N/256) = 391)
#define GROWS   8       // rows per wave in the register GEMM
#define GSPAN   8       // max graphs a 32-node pool block may span (LDS fallback guard)

typedef float v2f __attribute__((ext_vector_type(2)));

// exact RNE float -> bf16 pack
static __device__ __forceinline__ unsigned short f2bf(float f) {
    unsigned u = __float_as_uint(f);
    unsigned r = (u + 0x7FFFu + ((u >> 16) & 1u)) >> 16;
    return (unsigned short)r;
}
static __device__ __forceinline__ float bf_lo(unsigned u) { return __uint_as_float(u << 16); }
static __device__ __forceinline__ float bf_hi(unsigned u) { return __uint_as_float(u & 0xFFFF0000u); }

// ---- gemm1 body: rows x W1 -> bf16 (unscaled) ------------------------------------------------
static __device__ __forceinline__ void gemm_rows_bf(
        const float* __restrict__ X, const float* Wreg,
        unsigned short* __restrict__ Abf, int row0, int N, int lane) {
    #pragma unroll
    for (int j = 0; j < GROWS; ++j) {
        int row = row0 + j;
        if (row >= N) return;
        const float* xr = X + (size_t)row * 64;
        float acc = 0.0f;
        #pragma unroll
        for (int k = 0; k < 64; ++k) acc = fmaf(xr[k], Wreg[k], acc);
        Abf[(size_t)row * 64 + lane] = f2bf(acc);
    }
}

// ---- gemm2 body: rows x W2, *dis, pack fp8 e4m3 via HW cvt -----------------------------------
static __device__ __forceinline__ void gemm_rows_fp8(
        const float* __restrict__ X, const float* Wreg,
        unsigned* __restrict__ A8, const float* __restrict__ dis,
        int row0, int N, int lane) {
    #pragma unroll
    for (int j = 0; j < GROWS; ++j) {
        int row = row0 + j;
        if (row >= N) return;
        const float* xr = X + (size_t)row * 64;
        float acc = 0.0f;
        #pragma unroll
        for (int k = 0; k < 64; ++k) acc = fmaf(xr[k], Wreg[k], acc);
        acc *= dis[row];
        // cross-lane pack: features 4k..4k+3 -> one dword, stored by lane 4k
        float nb1 = __shfl_xor(acc, 1, 64);
        float lo = (lane & 1) ? nb1 : acc;
        float hi = (lane & 1) ? acc : nb1;
        int pk = __builtin_amdgcn_cvt_pk_fp8_f32(lo, hi, 0, false);   // 2 fp8 in low16
        int pk2 = __shfl_xor(pk, 2, 64);
        unsigned dw = (lane & 2) ? (((unsigned)pk2 & 0xFFFFu) | ((unsigned)pk << 16))
                                 : (((unsigned)pk & 0xFFFFu) | ((unsigned)pk2 << 16));
        if ((lane & 3) == 0) A8[(size_t)row * 16 + (lane >> 2)] = dw;
    }
}

// ---- pass A1 hybrid: blocks [0,Gg) = gemm1 (bf16); [Gg,Gg+NBLK) = bucket histogram -----------
__global__ __launch_bounds__(256) void hybrid_gemm_hist_kernel(
        const float* __restrict__ X, const float* __restrict__ W,
        unsigned short* __restrict__ Abf,
        const int* __restrict__ dst, int* __restrict__ bhist,
        int N, int E, int Gg, int nb2, int CE) {
    __shared__ int hist[MAXB];
    int t = threadIdx.x;
    if ((int)blockIdx.x < Gg) {
        int lane = t & 63;
        float Wreg[64];
        #pragma unroll
        for (int k = 0; k < 64; ++k) Wreg[k] = W[k * 64 + lane];
        int wave = __builtin_amdgcn_readfirstlane(blockIdx.x * 4 + (t >> 6));
        gemm_rows_bf(X, Wreg, Abf, wave * GROWS, N, lane);
    } else {
        int blk = blockIdx.x - Gg;               // 0..NBLK-1
        for (int i = t; i < nb2; i += 256) hist[i] = 0;
        __syncthreads();
        int e0 = blk * CE, e1 = min(e0 + CE, E);
        for (int e = e0 + t; e < e1; e += 256) atomicAdd(&hist[dst[e] >> 8], 1);
        __syncthreads();
        for (int i = t; i < nb2; i += 256) bhist[blk * nb2 + i] = hist[i];
    }
}

// ---- pass A2a: exclusive scan down each bucket column of bhist (nblk=512 fixed) --------------
__global__ __launch_bounds__(256) void scan_cols_kernel(
        int* __restrict__ bhist, int* __restrict__ ctot, int nb2) {
    __shared__ int sd[256];
    int c = blockIdx.x;
    int t = threadIdx.x;
    int v0 = bhist[t * nb2 + c];
    int v1 = bhist[(t + 256) * nb2 + c];
    int tsum = v0 + v1;
    sd[t] = tsum; __syncthreads();
    for (int off = 1; off < 256; off <<= 1) {
        int u = (t >= off) ? sd[t - off] : 0;
        __syncthreads();
        sd[t] += u;
        __syncthreads();
    }
    int excl = sd[t] - tsum;
    bhist[t * nb2 + c] = excl;
    bhist[(t + 256) * nb2 + c] = excl + v0;
    if (t == 255) ctot[c] = sd[255];
}

// ---- pass A2b merged: block 0 = scan of bucket totals -> cbase; block 1 = gstart -------------
__global__ void scan_gstart_kernel(const int* __restrict__ ctot, int* __restrict__ cbase,
                                   const int* __restrict__ batch, int* __restrict__ gstart,
                                   int nb2, int N) {
    if (blockIdx.x == 0) {
        int lane = threadIdx.x;
        if (lane >= 64) return;
        int base = lane * 8;
        int vals[8];
        int s = 0;
        #pragma unroll
        for (int k = 0; k < 8; ++k) {
            int i = base + k;
            int v = (i < nb2) ? ctot[i] : 0;
            vals[k] = s; s += v;
        }
        int inc = s;
        for (int off = 1; off < 64; off <<= 1) {
            int u = __shfl_up(inc, off, 64);
            if (lane >= off) inc += u;
        }
        int lexcl = inc - s;
        #pragma unroll
        for (int k = 0; k < 8; ++k) {
            int i = base + k;
            if (i <= nb2) cbase[i] = lexcl + vals[k];
        }
    } else {
        int g = threadIdx.x;
        if (g > NGRAPH) return;
        int lo = 0, hi = N;
        while (lo < hi) {
            int mid = (lo + hi) >> 1;
            if (batch[mid] < g) lo = mid + 1; else hi = mid;
        }
        gstart[g] = lo;
    }
}

// ---- pass A3: scatter edges into dst-buckets, packed (src<<8 | dst&255) ----------------------
__global__ __launch_bounds__(256) void scatter_sorted_kernel(
        const int* __restrict__ src, const int* __restrict__ dst,
        const int* __restrict__ bhist, const int* __restrict__ cbase,
        unsigned* __restrict__ ebuf, int E, int nb2, int CE) {
    __shared__ int cur[MAXB];
    int blk = blockIdx.x, t = threadIdx.x;
    for (int i = t; i < nb2; i += 256) cur[i] = bhist[blk * nb2 + i] + cbase[i];
    __syncthreads();
    int e0 = blk * CE, e1 = min(e0 + CE, E);
    for (int e = e0 + t; e < e1; e += 256) {
        int d = dst[e];
        int pos = atomicAdd(&cur[d >> 8], 1);
        ebuf[pos] = ((unsigned)src[e] << 8) | (unsigned)(d & 255);
    }
}

// ---- pass B: per bucket: CSR col/rowptr/degi/dis + convert A bf16 -> fp8 (x dis) -------------
__global__ __launch_bounds__(256) void build_csr_kernel(
        const unsigned* __restrict__ ebuf, const int* __restrict__ cbase,
        int* __restrict__ col, int* __restrict__ rowptr,
        int* __restrict__ degi, float* __restrict__ dis,
        const unsigned* __restrict__ Abf32, unsigned* __restrict__ A8, int N) {
    __shared__ int cnt[256];
    __shared__ int loff[256];
    __shared__ float disS[256];
    int b = blockIdx.x, t = threadIdx.x;
    int e0 = cbase[b], e1 = cbase[b + 1];
    cnt[t] = 0; __syncthreads();
    for (int i = e0 + t; i < e1; i += 256) atomicAdd(&cnt[ebuf[i] & 255u], 1);
    __syncthreads();
    int v = cnt[t];
    loff[t] = v; __syncthreads();
    for (int off = 1; off < 256; off <<= 1) {
        int u = (t >= off) ? loff[t - off] : 0;
        __syncthreads();
        loff[t] += u;
        __syncthreads();
    }
    int excl = loff[t] - v;
    int node = b * 256 + t;
    float ds = rsqrtf((float)v + 1.0f);
    disS[t] = ds;
    if (node < N) {
        degi[node]   = v;
        dis[node]    = ds;
        rowptr[node] = e0 + excl;
    }
    __syncthreads();
    cnt[t] = excl;              // reuse as local cursor
    __syncthreads();
    for (int i = e0 + t; i < e1; i += 256) {
        unsigned p = ebuf[i];
        int pos = atomicAdd(&cnt[p & 255u], 1);
        col[e0 + pos] = (int)(p >> 8);
    }
    // convert this bucket's A rows: bf16 * dis -> fp8 (16 dwords/row out)
    int base8 = b * 256 * 16;
    for (int i = t; i < 256 * 16; i += 256) {
        int r = i >> 4;               // row in bucket
        int dwo = i & 15;             // output dword (4 feats)
        int nd = b * 256 + r;
        if (nd < N) {
            float d2 = disS[r];
            unsigned u0 = Abf32[(size_t)nd * 32 + dwo * 2];
            unsigned u1 = Abf32[(size_t)nd * 32 + dwo * 2 + 1];
            int dw = __builtin_amdgcn_cvt_pk_fp8_f32(bf_lo(u0) * d2, bf_hi(u0) * d2, 0, false);
            dw = __builtin_amdgcn_cvt_pk_fp8_f32(bf_lo(u1) * d2, bf_hi(u1) * d2, dw, true);
            A8[base8 + i] = (unsigned)dw;
        }
    }
}

// ---- shared gather core: 8 nodes/wave, feature-sliced, fp8, acc init = self row --------------
static __device__ __forceinline__ void gather_node(
        const unsigned* __restrict__ A8, const int* __restrict__ col,
        int beg, int deg, int node, int f8, float acc[8]) {
    const char* Abase = (const char*)A8 + f8 * 8;
    uint2 an = *(const uint2*)(Abase + ((size_t)node << 6));
    v2f a0 = __builtin_amdgcn_cvt_pk_f32_fp8(an.x, false);
    v2f a1 = __builtin_amdgcn_cvt_pk_f32_fp8(an.x, true);
    v2f a2 = __builtin_amdgcn_cvt_pk_f32_fp8(an.y, false);
    v2f a3 = __builtin_amdgcn_cvt_pk_f32_fp8(an.y, true);
    acc[0] = a0.x; acc[1] = a0.y; acc[2] = a1.x; acc[3] = a1.y;
    acc[4] = a2.x; acc[5] = a2.y; acc[6] = a3.x; acc[7] = a3.y;
    int j = 0;
    for (; j + 4 <= deg; j += 4) {               // 4 gathers in flight per lane
        int s0 = col[beg + j]     << 6;
        int s1 = col[beg + j + 1] << 6;
        int s2 = col[beg + j + 2] << 6;
        int s3 = col[beg + j + 3] << 6;
        uint2 v0 = *(const uint2*)(Abase + s0);
        uint2 v1 = *(const uint2*)(Abase + s1);
        uint2 v2 = *(const uint2*)(Abase + s2);
        uint2 v3 = *(const uint2*)(Abase + s3);
        v2f f0, f1, f2, f3;
        f0 = __builtin_amdgcn_cvt_pk_f32_fp8(v0.x, false); acc[0] += f0.x; acc[1] += f0.y;
        f1 = __builtin_amdgcn_cvt_pk_f32_fp8(v0.x, true);  acc[2] += f1.x; acc[3] += f1.y;
        f2 = __builtin_amdgcn_cvt_pk_f32_fp8(v0.y, false); acc[4] += f2.x; acc[5] += f2.y;
        f3 = __builtin_amdgcn_cvt_pk_f32_fp8(v0.y, true);  acc[6] += f3.x; acc[7] += f3.y;
        f0 = __builtin_amdgcn_cvt_pk_f32_fp8(v1.x, false); acc[0] += f0.x; acc[1] += f0.y;
        f1 = __builtin_amdgcn_cvt_pk_f32_fp8(v1.x, true);  acc[2] += f1.x; acc[3] += f1.y;
        f2 = __builtin_amdgcn_cvt_pk_f32_fp8(v1.y, false); acc[4] += f2.x; acc[5] += f2.y;
        f3 = __builtin_amdgcn_cvt_pk_f32_fp8(v1.y, true);  acc[6] += f3.x; acc[7] += f3.y;
        f0 = __builtin_amdgcn_cvt_pk_f32_fp8(v2.x, false); acc[0] += f0.x; acc[1] += f0.y;
        f1 = __builtin_amdgcn_cvt_pk_f32_fp8(v2.x, true);  acc[2] += f1.x; acc[3] += f1.y;
        f2 = __builtin_amdgcn_cvt_pk_f32_fp8(v2.y, false); acc[4] += f2.x; acc[5] += f2.y;
        f3 = __builtin_amdgcn_cvt_pk_f32_fp8(v2.y, true);  acc[6] += f3.x; acc[7] += f3.y;
        f0 = __builtin_amdgcn_cvt_pk_f32_fp8(v3.x, false); acc[0] += f0.x; acc[1] += f0.y;
        f1 = __builtin_amdgcn_cvt_pk_f32_fp8(v3.x, true);  acc[2] += f1.x; acc[3] += f1.y;
        f2 = __builtin_amdgcn_cvt_pk_f32_fp8(v3.y, false); acc[4] += f2.x; acc[5] += f2.y;
        f3 = __builtin_amdgcn_cvt_pk_f32_fp8(v3.y, true);  acc[6] += f3.x; acc[7] += f3.y;
    }
    for (; j < deg; ++j) {
        int s = col[beg + j] << 6;
        uint2 v = *(const uint2*)(Abase + s);
        v2f f0 = __builtin_amdgcn_cvt_pk_f32_fp8(v.x, false);
        v2f f1 = __builtin_amdgcn_cvt_pk_f32_fp8(v.x, true);
        v2f f2 = __builtin_amdgcn_cvt_pk_f32_fp8(v.y, false);
        v2f f3 = __builtin_amdgcn_cvt_pk_f32_fp8(v.y, true);
        acc[0] += f0.x; acc[1] += f0.y; acc[2] += f1.x; acc[3] += f1.y;
        acc[4] += f2.x; acc[5] += f2.y; acc[6] += f3.x; acc[7] += f3.y;
    }
}

// ---- pull1 (CSR, fp8 gather, 8 nodes/wave, feature-sliced): h1 -> fp32 B ---------------------
__global__ __launch_bounds__(256) void pull_csr_kernel(
        const unsigned* __restrict__ A8, float* __restrict__ B,
        const int* __restrict__ rowptr, const int* __restrict__ degi,
        const float* __restrict__ dis, const float* __restrict__ bias,
        const int* __restrict__ col, int N) {
    int wave = (blockIdx.x * blockDim.x + threadIdx.x) >> 6;
    int lane = threadIdx.x & 63;
    int i = lane >> 3;
    int f8 = lane & 7;
    int node = wave * 8 + i;
    bool valid = node < N;
    if (!valid) node = N - 1;
    int deg = degi[node];
    int beg = rowptr[node];
    float acc[8];
    gather_node(A8, col, beg, deg, node, f8, acc);
    float d = dis[node];
    float4 b0 = ((const float4*)bias)[f8 * 2];
    float4 b1 = ((const float4*)bias)[f8 * 2 + 1];
    float4 r0, r1;
    r0.x = fmaxf(d * acc[0] + b0.x, 0.f);
    r0.y = fmaxf(d * acc[1] + b0.y, 0.f);
    r0.z = fmaxf(d * acc[2] + b0.z, 0.f);
    r0.w = fmaxf(d * acc[3] + b0.w, 0.f);
    r1.x = fmaxf(d * acc[4] + b1.x, 0.f);
    r1.y = fmaxf(d * acc[5] + b1.y, 0.f);
    r1.z = fmaxf(d * acc[6] + b1.z, 0.f);
    r1.w = fmaxf(d * acc[7] + b1.w, 0.f);
    if (valid) {
        *(float4*)(B + (size_t)node * 64 + f8 * 8)     = r0;
        *(float4*)(B + (size_t)node * 64 + f8 * 8 + 4) = r1;
    }
}

// ---- pull2 FUSED with pool: h2 accumulated into gsum via per-block LDS (batch-sorted) --------
__global__ __launch_bounds__(256) void pull_pool_kernel(
        const unsigned* __restrict__ A8,
        const int* __restrict__ rowptr, const int* __restrict__ degi,
        const float* __restrict__ dis, const float* __restrict__ bias,
        const int* __restrict__ col, const int* __restrict__ batch,
        float* __restrict__ gsum, int N) {
    __shared__ float gacc[GSPAN * 64];
    int t = threadIdx.x;
    for (int k = t; k < GSPAN * 64; k += 256) gacc[k] = 0.f;
    int n0 = blockIdx.x * 32;
    int g0 = batch[min(n0, N - 1)];
    int span = batch[min(n0 + 31, N - 1)] - g0;   // graphs spanned by this block (usually 0-1)
    __syncthreads();
    int wave = (blockIdx.x * blockDim.x + threadIdx.x) >> 6;
    int lane = t & 63;
    int i = lane >> 3;
    int f8 = lane & 7;
    int node = wave * 8 + i;
    bool valid = node < N;
    if (!valid) node = N - 1;
    int deg = degi[node];
    int beg = rowptr[node];
    float acc[8];
    gather_node(A8, col, beg, deg, node, f8, acc);
    float d = dis[node];
    float4 b0 = ((const float4*)bias)[f8 * 2];
    float4 b1 = ((const float4*)bias)[f8 * 2 + 1];
    float r[8];
    r[0] = fmaxf(d * acc[0] + b0.x, 0.f);
    r[1] = fmaxf(d * acc[1] + b0.y, 0.f);
    r[2] = fmaxf(d * acc[2] + b0.z, 0.f);
    r[3] = fmaxf(d * acc[3] + b0.w, 0.f);
    r[4] = fmaxf(d * acc[4] + b1.x, 0.f);
    r[5] = fmaxf(d * acc[5] + b1.y, 0.f);
    r[6] = fmaxf(d * acc[6] + b1.z, 0.f);
    r[7] = fmaxf(d * acc[7] + b1.w, 0.f);
    if (valid) {
        int g = batch[node];
        if (span < GSPAN) {
            int base = (g - g0) * 64 + f8 * 8;
            #pragma unroll
            for (int c = 0; c < 8; ++c) atomicAdd(&gacc[base + c], r[c]);
        } else {   // pathological span (tiny graphs) — direct global atomics, still correct
            #pragma unroll
            for (int c = 0; c < 8; ++c) unsafeAtomicAdd(&gsum[g * 64 + f8 * 8 + c], r[c]);
        }
    }
    __syncthreads();
    if (span < GSPAN) {
        int lim = (span + 1) * 64;
        for (int k = t; k < lim; k += 256) {
            float v = gacc[k];
            if (v != 0.f) unsafeAtomicAdd(&gsum[g0 * 64 + k], v);
        }
    }
}

// ---- GEMM2: A8[i][:] = fp8((sum_k H[i][k] * W[k][f]) * dis[i]) -------------------------------
__global__ __launch_bounds__(256) void gemm_scale_kernel(
        const float* __restrict__ X, const float* __restrict__ W,
        const float* __restrict__ dis, unsigned* __restrict__ A8, int N) {
    int lane = threadIdx.x & 63;
    float Wreg[64];
    #pragma unroll
    for (int k = 0; k < 64; ++k) Wreg[k] = W[k * 64 + lane];
    int wave = __builtin_amdgcn_readfirstlane(blockIdx.x * 4 + (threadIdx.x >> 6));
    gemm_rows_fp8(X, Wreg, A8, dis, wave * GROWS, N, lane);
}

// ---- head: counts derived from gstart --------------------------------------------------------
__global__ __launch_bounds__(256) void head_kernel(
        const float* __restrict__ gsum, const int* __restrict__ gstart,
        const float* __restrict__ topo, const float* __restrict__ Wlin,
        const float* __restrict__ blin, float* __restrict__ out) {
    int t = threadIdx.x;              // 256 = 64 graphs x 4 classes
    int g = t >> 2;
    int c = t & 3;
    float cntf = (float)(gstart[g + 1] - gstart[g]);
    float inv = 1.0f / fmaxf(cntf, 1.0f);
    float v = blin[c];
    #pragma unroll
    for (int f = 0; f < 64; ++f) v += gsum[g * 64 + f] * inv * Wlin[f * 4 + c];
    #pragma unroll
    for (int t2 = 0; t2 < TOPO_D; ++t2) v += topo[g * TOPO_D + t2] * Wlin[(64 + t2) * 4 + c];
    out[g * 4 + c] = v;
}

extern "C" void kernel_launch(void* const* d_in, const int* in_sizes, int n_in,
                              void* d_out, int out_size, void* d_ws, size_t ws_size,
                              hipStream_t stream) {
    const float* x     = (const float*)d_in[0];
    const int*   ei    = (const int*)d_in[1];
    const int*   batch = (const int*)d_in[2];
    const float* topo  = (const float*)d_in[3];
    const float* W1    = (const float*)d_in[4];
    const float* b1    = (const float*)d_in[5];
    const float* W2    = (const float*)d_in[6];
    const float* b2    = (const float*)d_in[7];
    const float* Wlin  = (const float*)d_in[8];
    const float* blin  = (const float*)d_in[9];
    float* out = (float*)d_out;

    const int N = in_sizes[0] / 64;      // 100000
    const int E = in_sizes[1] / 2;       // 1600000
    const int* src = ei;
    const int* dst = ei + E;
    const int nb2 = (N + 255) / 256;     // 391 dst-buckets of 256 nodes
    const int CE  = (E + NBLK - 1) / NBLK;

    // workspace layout (bytes)
    char* ws = (char*)d_ws;
    size_t off = 0;
    unsigned short* Abf = (unsigned short*)(ws + off); off += (size_t)N * 64 * 2;   // 12.8 MB (gemm1 bf16)
    unsigned* A8     = (unsigned*)(ws + off); off += (size_t)N * 64;                // 6.4 MB (fp8 gather)
    float*    B      = (float*)   (ws + off); off += (size_t)N * 64 * 4;            // 25.6 MB (h1 fp32)
    int*      col    = (int*)     (ws + off); off += (size_t)E * 4;                 // 6.4 MB
    unsigned* ebuf   = (unsigned*)(ws + off); off += (size_t)E * 4;                 // 6.4 MB
    int*      bhist  = (int*)     (ws + off); off += (size_t)NBLK * nb2 * 4;        // 0.8 MB
    int*      ctot   = (int*)     (ws + off); off += (size_t)(nb2 + 8) * 4;
    int*      cbase  = (int*)     (ws + off); off += (size_t)(nb2 + 8) * 4;
    int*      rowptr = (int*)     (ws + off); off += (size_t)(N + 1) * 4;
    int*      degi   = (int*)     (ws + off); off += (size_t)N * 4;
    float*    dis    = (float*)   (ws + off); off += (size_t)N * 4;
    int*      gstart = (int*)     (ws + off); off += (size_t)(NGRAPH + 8) * 4;
    float*    gsum   = (float*)   (ws + off); off += (size_t)NGRAPH * 64 * 4;

    // zero pool accumulators (ws is poisoned with 0xAA every call)
    hipMemsetAsync(gsum, 0, (size_t)NGRAPH * 64 * 4, stream);

    // ---- build: gemm1+histogram -> column scan -> (base scan | gstart) -> scatter -> CSR -----
    const int nWaves = (N + GROWS - 1) / GROWS;  // 12500
    const int Gg = (nWaves + 3) / 4;             // 3125 gemm blocks
    hybrid_gemm_hist_kernel<<<Gg + NBLK, 256, 0, stream>>>(x, W1, Abf, dst, bhist, N, E, Gg, nb2, CE);
    scan_cols_kernel<<<nb2, 256, 0, stream>>>(bhist, ctot, nb2);
    scan_gstart_kernel<<<2, 256, 0, stream>>>(ctot, cbase, batch, gstart, nb2, N);
    scatter_sorted_kernel<<<NBLK, 256, 0, stream>>>(src, dst, bhist, cbase, ebuf, E, nb2, CE);
    build_csr_kernel<<<nb2, 256, 0, stream>>>(ebuf, cbase, col, rowptr, degi, dis,
                                              (const unsigned*)Abf, A8, N);

    // ---- layer 1 pull (fp8 gather, 8 nodes/wave) ----
    int pullBlocks = ((N + 7) / 8 + 3) / 4;      // 3125
    pull_csr_kernel<<<pullBlocks, 256, 0, stream>>>(A8, B, rowptr, degi, dis, b1, col, N);

    // ---- layer 2: gemm2 then pull2 fused with pool ----
    gemm_scale_kernel<<<Gg, 256, 0, stream>>>(B, W2, dis, A8, N);
    pull_pool_kernel<<<pullBlocks, 256, 0, stream>>>(A8, rowptr, degi, dis, b2, col,
                                                     batch, gsum, N);

    // ---- head ----
    head_kernel<<<1, 256, 0, stream>>>(gsum, gstart, topo, Wlin, blin, out);
}

// Round 17
// 244.326 us; speedup vs baseline: 1.0941x; 1.0941x over previous
//
#include <hip/hip_runtime.h>
#include <hip/hip_bf16.h>

#define NGRAPH  64
#define TOPO_D  16
#define NBLK    512     // binning blocks (pass A); E=1.6M -> 3125 edges/block
#define MAXB    512     // LDS cap for bucket arrays (nb2 = ceil(N/256) = 391)
#define GROWS   8       // rows per wave in the register GEMM
#define PCH     16      // chunks per graph in pool

typedef float v2f __attribute__((ext_vector_type(2)));

// exact RNE float -> bf16 pack
static __device__ __forceinline__ unsigned f2bf(float f) {
    unsigned u = __float_as_uint(f);
    return (u + 0x7FFFu + ((u >> 16) & 1u)) >> 16;
}
static __device__ __forceinline__ float bf_lo(unsigned u) { return __uint_as_float(u << 16); }
static __device__ __forceinline__ float bf_hi(unsigned u) { return __uint_as_float(u & 0xFFFF0000u); }

// ---- gemm1 body: fp32 rows x W1 -> bf16 (unscaled) -------------------------------------------
static __device__ __forceinline__ void gemm_rows_bf(
        const float* __restrict__ X, const float* Wreg,
        unsigned short* __restrict__ Abf, int row0, int N, int lane) {
    #pragma unroll
    for (int j = 0; j < GROWS; ++j) {
        int row = row0 + j;
        if (row >= N) return;
        const float* xr = X + (size_t)row * 64;
        float acc = 0.0f;
        #pragma unroll
        for (int k = 0; k < 64; ++k) acc = fmaf(xr[k], Wreg[k], acc);
        Abf[(size_t)row * 64 + lane] = (unsigned short)f2bf(acc);
    }
}

// ---- gemm2 body: bf16 rows x W2, *dis, pack fp8 e4m3 via HW cvt ------------------------------
static __device__ __forceinline__ void gemm_rows_fp8(
        const unsigned* __restrict__ X32, const float* Wreg,
        unsigned* __restrict__ A8, const float* __restrict__ dis,
        int row0, int N, int lane) {
    #pragma unroll
    for (int j = 0; j < GROWS; ++j) {
        int row = row0 + j;
        if (row >= N) return;
        const unsigned* xr = X32 + (size_t)row * 32;   // wave-uniform -> s_load
        float acc = 0.0f;
        #pragma unroll
        for (int k = 0; k < 32; ++k) {
            unsigned u = xr[k];
            acc = fmaf(bf_lo(u), Wreg[2 * k], acc);
            acc = fmaf(bf_hi(u), Wreg[2 * k + 1], acc);
        }
        acc *= dis[row];
        // cross-lane pack: features 4k..4k+3 -> one dword, stored by lane 4k
        float nb1 = __shfl_xor(acc, 1, 64);
        float lo = (lane & 1) ? nb1 : acc;
        float hi = (lane & 1) ? acc : nb1;
        int pk = __builtin_amdgcn_cvt_pk_fp8_f32(lo, hi, 0, false);   // 2 fp8 in low16
        int pk2 = __shfl_xor(pk, 2, 64);
        unsigned dw = (lane & 2) ? (((unsigned)pk2 & 0xFFFFu) | ((unsigned)pk << 16))
                                 : (((unsigned)pk & 0xFFFFu) | ((unsigned)pk2 << 16));
        if ((lane & 3) == 0) A8[(size_t)row * 16 + (lane >> 2)] = dw;
    }
}

// ---- pass A1 hybrid: blocks [0,Gg) = gemm1 (bf16); [Gg,Gg+NBLK) = bucket histogram -----------
__global__ __launch_bounds__(256) void hybrid_gemm_hist_kernel(
        const float* __restrict__ X, const float* __restrict__ W,
        unsigned short* __restrict__ Abf,
        const int* __restrict__ dst, int* __restrict__ bhist,
        int N, int E, int Gg, int nb2, int CE) {
    __shared__ int hist[MAXB];
    int t = threadIdx.x;
    if ((int)blockIdx.x < Gg) {
        int lane = t & 63;
        float Wreg[64];
        #pragma unroll
        for (int k = 0; k < 64; ++k) Wreg[k] = W[k * 64 + lane];
        int wave = __builtin_amdgcn_readfirstlane(blockIdx.x * 4 + (t >> 6));
        gemm_rows_bf(X, Wreg, Abf, wave * GROWS, N, lane);
    } else {
        int blk = blockIdx.x - Gg;               // 0..NBLK-1
        for (int i = t; i < nb2; i += 256) hist[i] = 0;
        __syncthreads();
        int e0 = blk * CE, e1 = min(e0 + CE, E);
        for (int e = e0 + t; e < e1; e += 256) atomicAdd(&hist[dst[e] >> 8], 1);
        __syncthreads();
        for (int i = t; i < nb2; i += 256) bhist[blk * nb2 + i] = hist[i];
    }
}

// ---- pass A2a: exclusive scan down each bucket column of bhist (nblk=512 fixed) --------------
__global__ __launch_bounds__(256) void scan_cols_kernel(
        int* __restrict__ bhist, int* __restrict__ ctot, int nb2) {
    __shared__ int sd[256];
    int c = blockIdx.x;
    int t = threadIdx.x;
    int v0 = bhist[t * nb2 + c];
    int v1 = bhist[(t + 256) * nb2 + c];
    int tsum = v0 + v1;
    sd[t] = tsum; __syncthreads();
    for (int off = 1; off < 256; off <<= 1) {
        int u = (t >= off) ? sd[t - off] : 0;
        __syncthreads();
        sd[t] += u;
        __syncthreads();
    }
    int excl = sd[t] - tsum;
    bhist[t * nb2 + c] = excl;
    bhist[(t + 256) * nb2 + c] = excl + v0;
    if (t == 255) ctot[c] = sd[255];
}

// ---- pass A2b merged: block 0 = scan of bucket totals -> cbase; block 1 = gstart -------------
__global__ void scan_gstart_kernel(const int* __restrict__ ctot, int* __restrict__ cbase,
                                   const int* __restrict__ batch, int* __restrict__ gstart,
                                   int nb2, int N) {
    if (blockIdx.x == 0) {
        int lane = threadIdx.x;
        if (lane >= 64) return;
        int base = lane * 8;
        int vals[8];
        int s = 0;
        #pragma unroll
        for (int k = 0; k < 8; ++k) {
            int i = base + k;
            int v = (i < nb2) ? ctot[i] : 0;
            vals[k] = s; s += v;
        }
        int inc = s;
        for (int off = 1; off < 64; off <<= 1) {
            int u = __shfl_up(inc, off, 64);
            if (lane >= off) inc += u;
        }
        int lexcl = inc - s;
        #pragma unroll
        for (int k = 0; k < 8; ++k) {
            int i = base + k;
            if (i <= nb2) cbase[i] = lexcl + vals[k];
        }
    } else {
        int g = threadIdx.x;
        if (g > NGRAPH) return;
        int lo = 0, hi = N;
        while (lo < hi) {
            int mid = (lo + hi) >> 1;
            if (batch[mid] < g) lo = mid + 1; else hi = mid;
        }
        gstart[g] = lo;
    }
}

// ---- pass A3: scatter edges into dst-buckets, packed (src<<8 | dst&255) ----------------------
__global__ __launch_bounds__(256) void scatter_sorted_kernel(
        const int* __restrict__ src, const int* __restrict__ dst,
        const int* __restrict__ bhist, const int* __restrict__ cbase,
        unsigned* __restrict__ ebuf, int E, int nb2, int CE) {
    __shared__ int cur[MAXB];
    int blk = blockIdx.x, t = threadIdx.x;
    for (int i = t; i < nb2; i += 256) cur[i] = bhist[blk * nb2 + i] + cbase[i];
    __syncthreads();
    int e0 = blk * CE, e1 = min(e0 + CE, E);
    for (int e = e0 + t; e < e1; e += 256) {
        int d = dst[e];
        int pos = atomicAdd(&cur[d >> 8], 1);
        ebuf[pos] = ((unsigned)src[e] << 8) | (unsigned)(d & 255);
    }
}

// ---- pass B: per bucket: CSR col/rowptr/degi/dis + convert A bf16 -> fp8 (x dis) -------------
__global__ __launch_bounds__(256) void build_csr_kernel(
        const unsigned* __restrict__ ebuf, const int* __restrict__ cbase,
        int* __restrict__ col, int* __restrict__ rowptr,
        int* __restrict__ degi, float* __restrict__ dis,
        const unsigned* __restrict__ Abf32, unsigned* __restrict__ A8, int N) {
    __shared__ int cnt[256];
    __shared__ int loff[256];
    __shared__ float disS[256];
    int b = blockIdx.x, t = threadIdx.x;
    int e0 = cbase[b], e1 = cbase[b + 1];
    cnt[t] = 0; __syncthreads();
    for (int i = e0 + t; i < e1; i += 256) atomicAdd(&cnt[ebuf[i] & 255u], 1);
    __syncthreads();
    int v = cnt[t];
    loff[t] = v; __syncthreads();
    for (int off = 1; off < 256; off <<= 1) {
        int u = (t >= off) ? loff[t - off] : 0;
        __syncthreads();
        loff[t] += u;
        __syncthreads();
    }
    int excl = loff[t] - v;
    int node = b * 256 + t;
    float ds = rsqrtf((float)v + 1.0f);
    disS[t] = ds;
    if (node < N) {
        degi[node]   = v;
        dis[node]    = ds;
        rowptr[node] = e0 + excl;
    }
    __syncthreads();
    cnt[t] = excl;              // reuse as local cursor
    __syncthreads();
    for (int i = e0 + t; i < e1; i += 256) {
        unsigned p = ebuf[i];
        int pos = atomicAdd(&cnt[p & 255u], 1);
        col[e0 + pos] = (int)(p >> 8);
    }
    // convert this bucket's A rows: bf16 * dis -> fp8 (16 dwords/row out)
    int base8 = b * 256 * 16;
    for (int i = t; i < 256 * 16; i += 256) {
        int r = i >> 4;               // row in bucket
        int dwo = i & 15;             // output dword (4 feats)
        int nd = b * 256 + r;
        if (nd < N) {
            float d2 = disS[r];
            unsigned u0 = Abf32[(size_t)nd * 32 + dwo * 2];
            unsigned u1 = Abf32[(size_t)nd * 32 + dwo * 2 + 1];
            int dw = __builtin_amdgcn_cvt_pk_fp8_f32(bf_lo(u0) * d2, bf_hi(u0) * d2, 0, false);
            dw = __builtin_amdgcn_cvt_pk_fp8_f32(bf_lo(u1) * d2, bf_hi(u1) * d2, dw, true);
            A8[base8 + i] = (unsigned)dw;
        }
    }
}

// ---- shared gather core: 8 nodes/wave, feature-sliced, fp8, acc init = self row --------------
static __device__ __forceinline__ void gather_node(
        const unsigned* __restrict__ A8, const int* __restrict__ col,
        int beg, int deg, int node, int f8, float acc[8]) {
    const char* Abase = (const char*)A8 + f8 * 8;
    uint2 an = *(const uint2*)(Abase + ((size_t)node << 6));
    v2f a0 = __builtin_amdgcn_cvt_pk_f32_fp8(an.x, false);
    v2f a1 = __builtin_amdgcn_cvt_pk_f32_fp8(an.x, true);
    v2f a2 = __builtin_amdgcn_cvt_pk_f32_fp8(an.y, false);
    v2f a3 = __builtin_amdgcn_cvt_pk_f32_fp8(an.y, true);
    acc[0] = a0.x; acc[1] = a0.y; acc[2] = a1.x; acc[3] = a1.y;
    acc[4] = a2.x; acc[5] = a2.y; acc[6] = a3.x; acc[7] = a3.y;
    int j = 0;
    for (; j + 4 <= deg; j += 4) {               // 4 gathers in flight per lane
        int s0 = col[beg + j]     << 6;
        int s1 = col[beg + j + 1] << 6;
        int s2 = col[beg + j + 2] << 6;
        int s3 = col[beg + j + 3] << 6;
        uint2 v0 = *(const uint2*)(Abase + s0);
        uint2 v1 = *(const uint2*)(Abase + s1);
        uint2 v2 = *(const uint2*)(Abase + s2);
        uint2 v3 = *(const uint2*)(Abase + s3);
        v2f f0, f1, f2, f3;
        f0 = __builtin_amdgcn_cvt_pk_f32_fp8(v0.x, false); acc[0] += f0.x; acc[1] += f0.y;
        f1 = __builtin_amdgcn_cvt_pk_f32_fp8(v0.x, true);  acc[2] += f1.x; acc[3] += f1.y;
        f2 = __builtin_amdgcn_cvt_pk_f32_fp8(v0.y, false); acc[4] += f2.x; acc[5] += f2.y;
        f3 = __builtin_amdgcn_cvt_pk_f32_fp8(v0.y, true);  acc[6] += f3.x; acc[7] += f3.y;
        f0 = __builtin_amdgcn_cvt_pk_f32_fp8(v1.x, false); acc[0] += f0.x; acc[1] += f0.y;
        f1 = __builtin_amdgcn_cvt_pk_f32_fp8(v1.x, true);  acc[2] += f1.x; acc[3] += f1.y;
        f2 = __builtin_amdgcn_cvt_pk_f32_fp8(v1.y, false); acc[4] += f2.x; acc[5] += f2.y;
        f3 = __builtin_amdgcn_cvt_pk_f32_fp8(v1.y, true);  acc[6] += f3.x; acc[7] += f3.y;
        f0 = __builtin_amdgcn_cvt_pk_f32_fp8(v2.x, false); acc[0] += f0.x; acc[1] += f0.y;
        f1 = __builtin_amdgcn_cvt_pk_f32_fp8(v2.x, true);  acc[2] += f1.x; acc[3] += f1.y;
        f2 = __builtin_amdgcn_cvt_pk_f32_fp8(v2.y, false); acc[4] += f2.x; acc[5] += f2.y;
        f3 = __builtin_amdgcn_cvt_pk_f32_fp8(v2.y, true);  acc[6] += f3.x; acc[7] += f3.y;
        f0 = __builtin_amdgcn_cvt_pk_f32_fp8(v3.x, false); acc[0] += f0.x; acc[1] += f0.y;
        f1 = __builtin_amdgcn_cvt_pk_f32_fp8(v3.x, true);  acc[2] += f1.x; acc[3] += f1.y;
        f2 = __builtin_amdgcn_cvt_pk_f32_fp8(v3.y, false); acc[4] += f2.x; acc[5] += f2.y;
        f3 = __builtin_amdgcn_cvt_pk_f32_fp8(v3.y, true);  acc[6] += f3.x; acc[7] += f3.y;
    }
    for (; j < deg; ++j) {
        int s = col[beg + j] << 6;
        uint2 v = *(const uint2*)(Abase + s);
        v2f f0 = __builtin_amdgcn_cvt_pk_f32_fp8(v.x, false);
        v2f f1 = __builtin_amdgcn_cvt_pk_f32_fp8(v.x, true);
        v2f f2 = __builtin_amdgcn_cvt_pk_f32_fp8(v.y, false);
        v2f f3 = __builtin_amdgcn_cvt_pk_f32_fp8(v.y, true);
        acc[0] += f0.x; acc[1] += f0.y; acc[2] += f1.x; acc[3] += f1.y;
        acc[4] += f2.x; acc[5] += f2.y; acc[6] += f3.x; acc[7] += f3.y;
    }
}

// ---- pull1 (CSR, fp8 gather, 8 nodes/wave, feature-sliced): h1 -> bf16 B ---------------------
__global__ __launch_bounds__(256) void pull_csr_kernel(
        const unsigned* __restrict__ A8, unsigned* __restrict__ Bbf,
        const int* __restrict__ rowptr, const int* __restrict__ degi,
        const float* __restrict__ dis, const float* __restrict__ bias,
        const int* __restrict__ col, int N) {
    int wave = (blockIdx.x * blockDim.x + threadIdx.x) >> 6;
    int lane = threadIdx.x & 63;
    int i = lane >> 3;
    int f8 = lane & 7;
    int node = wave * 8 + i;
    bool valid = node < N;
    if (!valid) node = N - 1;
    int deg = degi[node];
    int beg = rowptr[node];
    float acc[8];
    gather_node(A8, col, beg, deg, node, f8, acc);
    float d = dis[node];
    float4 b0 = ((const float4*)bias)[f8 * 2];
    float4 b1 = ((const float4*)bias)[f8 * 2 + 1];
    float r[8];
    r[0] = fmaxf(d * acc[0] + b0.x, 0.f);
    r[1] = fmaxf(d * acc[1] + b0.y, 0.f);
    r[2] = fmaxf(d * acc[2] + b0.z, 0.f);
    r[3] = fmaxf(d * acc[3] + b0.w, 0.f);
    r[4] = fmaxf(d * acc[4] + b1.x, 0.f);
    r[5] = fmaxf(d * acc[5] + b1.y, 0.f);
    r[6] = fmaxf(d * acc[6] + b1.z, 0.f);
    r[7] = fmaxf(d * acc[7] + b1.w, 0.f);
    if (valid) {
        uint4 o;
        o.x = f2bf(r[0]) | (f2bf(r[1]) << 16);
        o.y = f2bf(r[2]) | (f2bf(r[3]) << 16);
        o.z = f2bf(r[4]) | (f2bf(r[5]) << 16);
        o.w = f2bf(r[6]) | (f2bf(r[7]) << 16);
        *(uint4*)(Bbf + (size_t)node * 32 + f8 * 4) = o;
    }
}

// ---- pull2: identical gather, fp32 out to B2 (read by pool) ----------------------------------
__global__ __launch_bounds__(256) void pull2_csr_kernel(
        const unsigned* __restrict__ A8, float* __restrict__ B,
        const int* __restrict__ rowptr, const int* __restrict__ degi,
        const float* __restrict__ dis, const float* __restrict__ bias,
        const int* __restrict__ col, int N) {
    int wave = (blockIdx.x * blockDim.x + threadIdx.x) >> 6;
    int lane = threadIdx.x & 63;
    int i = lane >> 3;
    int f8 = lane & 7;
    int node = wave * 8 + i;
    bool valid = node < N;
    if (!valid) node = N - 1;
    int deg = degi[node];
    int beg = rowptr[node];
    float acc[8];
    gather_node(A8, col, beg, deg, node, f8, acc);
    float d = dis[node];
    float4 b0 = ((const float4*)bias)[f8 * 2];
    float4 b1 = ((const float4*)bias)[f8 * 2 + 1];
    float4 r0, r1;
    r0.x = fmaxf(d * acc[0] + b0.x, 0.f);
    r0.y = fmaxf(d * acc[1] + b0.y, 0.f);
    r0.z = fmaxf(d * acc[2] + b0.z, 0.f);
    r0.w = fmaxf(d * acc[3] + b0.w, 0.f);
    r1.x = fmaxf(d * acc[4] + b1.x, 0.f);
    r1.y = fmaxf(d * acc[5] + b1.y, 0.f);
    r1.z = fmaxf(d * acc[6] + b1.z, 0.f);
    r1.w = fmaxf(d * acc[7] + b1.w, 0.f);
    if (valid) {
        *(float4*)(B + (size_t)node * 64 + f8 * 8)     = r0;
        *(float4*)(B + (size_t)node * 64 + f8 * 8 + 4) = r1;
    }
}

// ---- GEMM2: bf16 h1 x W2 -> fp8 A8 -----------------------------------------------------------
__global__ __launch_bounds__(256) void gemm_scale_kernel(
        const unsigned* __restrict__ X32, const float* __restrict__ W,
        const float* __restrict__ dis, unsigned* __restrict__ A8, int N) {
    int lane = threadIdx.x & 63;
    float Wreg[64];
    #pragma unroll
    for (int k = 0; k < 64; ++k) Wreg[k] = W[k * 64 + lane];
    int wave = __builtin_amdgcn_readfirstlane(blockIdx.x * 4 + (threadIdx.x >> 6));
    gemm_rows_fp8(X32, Wreg, A8, dis, wave * GROWS, N, lane);
}

// ---- pool2: grid = NGRAPH x PCH chunks; contiguous streaming of fp32 h2 ----------------------
__global__ __launch_bounds__(256) void pool2_kernel(
        const float* __restrict__ H, const int* __restrict__ gstart,
        float* __restrict__ gsum) {
    __shared__ float red[4][64];
    int b = blockIdx.x;
    int g = b >> 4;                  // PCH = 16
    int c = b & 15;
    int s = gstart[g], e = gstart[g + 1];
    int len = e - s;
    int chunk = (len + PCH - 1) / PCH;
    int lo = s + c * chunk;
    int hi = min(lo + chunk, e);
    int w = threadIdx.x >> 6;
    int lane = threadIdx.x & 63;
    float acc0 = 0.f, acc1 = 0.f;
    int n = lo + w;
    for (; n + 4 < hi; n += 8) {     // 2 rows in flight per wave
        acc0 += H[(size_t)n * 64 + lane];
        acc1 += H[(size_t)(n + 4) * 64 + lane];
    }
    if (n < hi) acc0 += H[(size_t)n * 64 + lane];
    red[w][lane] = acc0 + acc1;
    __syncthreads();
    if (threadIdx.x < 64) {
        float v = red[0][threadIdx.x] + red[1][threadIdx.x]
                + red[2][threadIdx.x] + red[3][threadIdx.x];
        unsafeAtomicAdd(&gsum[g * 64 + threadIdx.x], v);
    }
}

// ---- head: counts derived from gstart --------------------------------------------------------
__global__ __launch_bounds__(256) void head_kernel(
        const float* __restrict__ gsum, const int* __restrict__ gstart,
        const float* __restrict__ topo, const float* __restrict__ Wlin,
        const float* __restrict__ blin, float* __restrict__ out) {
    int t = threadIdx.x;              // 256 = 64 graphs x 4 classes
    int g = t >> 2;
    int c = t & 3;
    float cntf = (float)(gstart[g + 1] - gstart[g]);
    float inv = 1.0f / fmaxf(cntf, 1.0f);
    float v = blin[c];
    #pragma unroll
    for (int f = 0; f < 64; ++f) v += gsum[g * 64 + f] * inv * Wlin[f * 4 + c];
    #pragma unroll
    for (int t2 = 0; t2 < TOPO_D; ++t2) v += topo[g * TOPO_D + t2] * Wlin[(64 + t2) * 4 + c];
    out[g * 4 + c] = v;
}

extern "C" void kernel_launch(void* const* d_in, const int* in_sizes, int n_in,
                              void* d_out, int out_size, void* d_ws, size_t ws_size,
                              hipStream_t stream) {
    const float* x     = (const float*)d_in[0];
    const int*   ei    = (const int*)d_in[1];
    const int*   batch = (const int*)d_in[2];
    const float* topo  = (const float*)d_in[3];
    const float* W1    = (const float*)d_in[4];
    const float* b1    = (const float*)d_in[5];
    const float* W2    = (const float*)d_in[6];
    const float* b2    = (const float*)d_in[7];
    const float* Wlin  = (const float*)d_in[8];
    const float* blin  = (const float*)d_in[9];
    float* out = (float*)d_out;

    const int N = in_sizes[0] / 64;      // 100000
    const int E = in_sizes[1] / 2;       // 1600000
    const int* src = ei;
    const int* dst = ei + E;
    const int nb2 = (N + 255) / 256;     // 391 dst-buckets of 256 nodes
    const int CE  = (E + NBLK - 1) / NBLK;

    // workspace layout (bytes)
    char* ws = (char*)d_ws;
    size_t off = 0;
    unsigned short* Abf = (unsigned short*)(ws + off); off += (size_t)N * 64 * 2;   // 12.8 MB (gemm1 bf16)
    unsigned* Bbf    = (unsigned*)(ws + off); off += (size_t)N * 32 * 4;            // 12.8 MB (h1 bf16)
    unsigned* A8     = (unsigned*)(ws + off); off += (size_t)N * 64;                // 6.4 MB (fp8 gather)
    float*    B2     = (float*)   (ws + off); off += (size_t)N * 64 * 4;            // 25.6 MB (h2 fp32)
    int*      col    = (int*)     (ws + off); off += (size_t)E * 4;                 // 6.4 MB
    unsigned* ebuf   = (unsigned*)(ws + off); off += (size_t)E * 4;                 // 6.4 MB
    int*      bhist  = (int*)     (ws + off); off += (size_t)NBLK * nb2 * 4;        // 0.8 MB
    int*      ctot   = (int*)     (ws + off); off += (size_t)(nb2 + 8) * 4;
    int*      cbase  = (int*)     (ws + off); off += (size_t)(nb2 + 8) * 4;
    int*      rowptr = (int*)     (ws + off); off += (size_t)(N + 1) * 4;
    int*      degi   = (int*)     (ws + off); off += (size_t)N * 4;
    float*    dis    = (float*)   (ws + off); off += (size_t)N * 4;
    int*      gstart = (int*)     (ws + off); off += (size_t)(NGRAPH + 8) * 4;
    float*    gsum   = (float*)   (ws + off); off += (size_t)NGRAPH * 64 * 4;

    // zero pool accumulators (ws is poisoned with 0xAA every call)
    hipMemsetAsync(gsum, 0, (size_t)NGRAPH * 64 * 4, stream);

    // ---- build: gemm1+histogram -> column scan -> (base scan | gstart) -> scatter -> CSR -----
    const int nWaves = (N + GROWS - 1) / GROWS;  // 12500
    const int Gg = (nWaves + 3) / 4;             // 3125 gemm blocks
    hybrid_gemm_hist_kernel<<<Gg + NBLK, 256, 0, stream>>>(x, W1, Abf, dst, bhist, N, E, Gg, nb2, CE);
    scan_cols_kernel<<<nb2, 256, 0, stream>>>(bhist, ctot, nb2);
    scan_gstart_kernel<<<2, 256, 0, stream>>>(ctot, cbase, batch, gstart, nb2, N);
    scatter_sorted_kernel<<<NBLK, 256, 0, stream>>>(src, dst, bhist, cbase, ebuf, E, nb2, CE);
    build_csr_kernel<<<nb2, 256, 0, stream>>>(ebuf, cbase, col, rowptr, degi, dis,
                                              (const unsigned*)Abf, A8, N);

    // ---- layer 1 pull (fp8 gather, 8 nodes/wave) -> bf16 h1 ----
    int pullBlocks = ((N + 7) / 8 + 3) / 4;      // 3125
    pull_csr_kernel<<<pullBlocks, 256, 0, stream>>>(A8, Bbf, rowptr, degi, dis, b1, col, N);

    // ---- layer 2: gemm2 (bf16 in, fp8 out) then pull2 (fp32 out) ----
    gemm_scale_kernel<<<Gg, 256, 0, stream>>>(Bbf, W2, dis, A8, N);
    pull2_csr_kernel<<<pullBlocks, 256, 0, stream>>>(A8, B2, rowptr, degi, dis, b2, col, N);

    // ---- pool + head ----
    pool2_kernel<<<NGRAPH * PCH, 256, 0, stream>>>(B2, gstart, gsum);
    head_kernel<<<1, 256, 0, stream>>>(gsum, gstart, topo, Wlin, blin, out);
}